// Round 13
// baseline (225.197 us; speedup 1.0000x reference)
//
#include <hip/hip_runtime.h>

#define IN_FEAT 256
#define OUT_FEAT 64
#define BBITS 5
#define BSZ 32                      // dsts per bucket
#define CAP_SLICE 256               // slots per (slice,bucket); mean 128, +11 sigma
#define CAP_BUCKET 1600             // LDS sort buffer records; mean 1024, +18 sigma
#define CNT_STRIDE 16               // one counter per 64B line

typedef __attribute__((ext_vector_type(8))) short bf16x8;
typedef __attribute__((ext_vector_type(4))) float f32x4;
typedef __attribute__((ext_vector_type(2))) float f32x2;

static __device__ __forceinline__ short f2bf(float f) {
    unsigned u = __float_as_uint(f);
    unsigned r = (u + 0x7FFFu + ((u >> 16) & 1u)) >> 16;
    return (short)r;
}
static __device__ __forceinline__ float bf2f(unsigned short u) {
    return __uint_as_float(((unsigned)u) << 16);
}
static __device__ __forceinline__ float bflo(unsigned v) {
    return __uint_as_float(v << 16);
}
static __device__ __forceinline__ float bfhi(unsigned v) {
    return __uint_as_float(v & 0xFFFF0000u);
}

// ---------------- Wfrag: pre-swizzle [Wself|Wneigh] into MFMA B-fragment order
__global__ __launch_bounds__(256) void wfrag_build(
    const float* __restrict__ Wself,
    const float* __restrict__ Wneigh,
    bf16x8* __restrict__ Wfrag)
{
    const int t = blockIdx.x * 256 + threadIdx.x;   // 0..4095
    const int kstep = t >> 9;
    const int ntile = (t >> 6) & 7;
    const int lane  = t & 63;
    const int quad  = lane >> 4;
    const int n     = ntile * 16 + (lane & 15);
    const float* src = (n < OUT_FEAT) ? (Wself + n) : (Wneigh + (n - OUT_FEAT));
    const int k0 = kstep * 32 + quad * 8;
    bf16x8 v;
#pragma unroll
    for (int j = 0; j < 8; ++j) v[j] = f2bf(src[(size_t)(k0 + j) * OUT_FEAT]);
    Wfrag[t] = v;
}

// ---------------- Fused GEMM + scatter ---------------------------------------
// Streaming reads (feat, edges) are nontemporal so they don't evict the
// binned write-frontier lines from L2 (WRITE_SIZE amplification fix).
__global__ __launch_bounds__(256) void gemm_scatter(
    const float* __restrict__ feat,
    const bf16x8* __restrict__ Wfrag,
    unsigned short* __restrict__ accSelf,  // [N,64] bf16
    unsigned short* __restrict__ Pn,       // [N,64] bf16
    const int* __restrict__ esrc,
    const int* __restrict__ edst,
    const float* __restrict__ ew,
    int* __restrict__ cnt,
    int2* __restrict__ binned,
    int n_nodes, int n_edges, int NB)
{
    // ---------------- phase A: GEMM tile ----------------
    {
        const int wave = threadIdx.x >> 6;
        const int lane = threadIdx.x & 63;
        const int quad = lane >> 4;
        const int l15  = lane & 15;
        const int row0 = blockIdx.x * 64 + wave * 16;

        if (row0 < n_nodes) {
            f32x4 c[8];
#pragma unroll
            for (int i = 0; i < 8; ++i) c[i] = (f32x4){0.f, 0.f, 0.f, 0.f};

            const int arow = min(row0 + l15, n_nodes - 1);
            const float* afeat = feat + (size_t)arow * IN_FEAT + quad * 8;

#pragma unroll
            for (int kstep = 0; kstep < 8; ++kstep) {
                const f32x4 x = __builtin_nontemporal_load((const f32x4*)(afeat + kstep * 32));
                const f32x4 y = __builtin_nontemporal_load((const f32x4*)(afeat + kstep * 32 + 4));
                bf16x8 a;
                a[0] = f2bf(x[0]); a[1] = f2bf(x[1]); a[2] = f2bf(x[2]); a[3] = f2bf(x[3]);
                a[4] = f2bf(y[0]); a[5] = f2bf(y[1]); a[6] = f2bf(y[2]); a[7] = f2bf(y[3]);
                bf16x8 b[8];
#pragma unroll
                for (int nt = 0; nt < 8; ++nt) b[nt] = Wfrag[(kstep * 8 + nt) * 64 + lane];
#pragma unroll
                for (int nt = 0; nt < 8; ++nt)
                    c[nt] = __builtin_amdgcn_mfma_f32_16x16x32_bf16(a, b[nt], c[nt], 0, 0, 0);
            }

            // C layout: col = (nt&3)*16 + (lane&15), row = row0 + quad*4 + reg
#pragma unroll
            for (int nt = 0; nt < 8; ++nt) {
                unsigned short* dst = (nt < 4) ? accSelf : Pn;
                const int col = (nt & 3) * 16 + l15;
#pragma unroll
                for (int r = 0; r < 4; ++r) {
                    const int row = row0 + quad * 4 + r;
                    if (row < n_nodes)
                        dst[(size_t)row * OUT_FEAT + col] = (unsigned short)f2bf(c[nt][r]);
                }
            }
        }
    }

    // ---------------- phase B: edge scatter ----------------
    {
        const int base  = blockIdx.x * 2048;
        const int slice = blockIdx.x & 7;
        int d[8], s[8], w[8], pos[8];
        bool ok[8];
#pragma unroll
        for (int k = 0; k < 8; ++k) {
            const int idx = base + k * 256 + (int)threadIdx.x;
            ok[k] = idx < n_edges;
            if (ok[k]) {
                d[k] = __builtin_nontemporal_load(edst + idx);
                s[k] = __builtin_nontemporal_load(esrc + idx);
                w[k] = __float_as_int(__builtin_nontemporal_load(ew + idx));
            }
        }
#pragma unroll
        for (int k = 0; k < 8; ++k)
            if (ok[k]) pos[k] = atomicAdd(&cnt[((size_t)slice * NB + (d[k] >> BBITS)) * CNT_STRIDE], 1);
#pragma unroll
        for (int k = 0; k < 8; ++k)
            if (ok[k] && pos[k] < CAP_SLICE)
                binned[((size_t)slice * NB + (d[k] >> BBITS)) * CAP_SLICE + pos[k]] =
                    make_int2(((d[k] & (BSZ - 1)) << 26) | s[k], w[k]);
    }
}

// ---------------- Fused sort+gather: one block per bucket --------------------
// Phase 3: half-wave per edge stream, dword (2-col) per lane, 8 edges in
// flight per half (16/wave) for deep MLP on the scattered Pn line fetches.
__global__ __launch_bounds__(256) void bucket_gather(
    const int2* __restrict__ binned,
    const int* __restrict__ cnt,
    const unsigned short* __restrict__ Pn,       // bf16
    const unsigned short* __restrict__ accSelf,  // bf16
    float* __restrict__ out, int n_nodes, int NB)
{
    __shared__ int2 sepk[CAP_BUCKET];     // 12.8 KB
    __shared__ int  scnt[8];
    __shared__ int  hcnt[BSZ];
    __shared__ int  hoff[BSZ + 1];
    __shared__ int  hcur[BSZ];

    const int b = blockIdx.x;
    const int t = threadIdx.x;

    if (t < 8) scnt[t] = min(cnt[((size_t)t * NB + b) * CNT_STRIDE], CAP_SLICE);
    if (t < BSZ) hcnt[t] = 0;
    __syncthreads();

    // phase 1: histogram of local dst (read .x only)
#pragma unroll
    for (int sl = 0; sl < 8; ++sl) {
        const int nrec = scnt[sl];
        const int2* rb = binned + ((size_t)sl * NB + b) * CAP_SLICE;
        for (int i = t; i < nrec; i += 256)
            atomicAdd(&hcnt[(unsigned)rb[i].x >> 26], 1);
    }
    __syncthreads();
    if (t == 0) {
        int run = 0;
#pragma unroll
        for (int k = 0; k < BSZ; ++k) { hoff[k] = run; run += hcnt[k]; }
        hoff[BSZ] = run;
    }
    __syncthreads();
    if (t < BSZ) hcur[t] = hoff[t];
    __syncthreads();

    // phase 2: scatter into sorted LDS positions
#pragma unroll
    for (int sl = 0; sl < 8; ++sl) {
        const int nrec = scnt[sl];
        const int2* rb = binned + ((size_t)sl * NB + b) * CAP_SLICE;
        for (int i = t; i < nrec; i += 256) {
            const int2 p = rb[i];
            const int pos = atomicAdd(&hcur[(unsigned)p.x >> 26], 1);
            if (pos < CAP_BUCKET) sepk[pos] = make_int2(p.x & 0x3FFFFFF, p.y);
        }
    }
    __syncthreads();

    // phase 3: wave per 8 dsts; half-wave per edge-substream; dword per lane.
    const int wv   = t >> 6;
    const int lane = t & 63;
    const int half = lane >> 5;          // 0: even edges, 1: odd edges
    const int c2   = (lane & 31) * 2;    // column pair

#pragma unroll
    for (int ldn = wv * 8; ldn < wv * 8 + 8; ++ldn) {
        const int dst = b * BSZ + ldn;
        if (dst >= n_nodes) break;
        const int beg = min(hoff[ldn], CAP_BUCKET);
        const int end = min(hoff[ldn + 1], CAP_BUCKET);

        float a0 = 0.f, a1 = 0.f, b0 = 0.f, b1 = 0.f;
        float g0 = 0.f, g1 = 0.f, h0 = 0.f, h1 = 0.f;
        int e = beg + half;
        for (; e + 14 < end; e += 16) {   // 8 edges per half per iter (16/wave)
            const int2 p0 = sepk[e + 0];
            const int2 p1 = sepk[e + 2];
            const int2 p2 = sepk[e + 4];
            const int2 p3 = sepk[e + 6];
            const int2 p4 = sepk[e + 8];
            const int2 p5 = sepk[e + 10];
            const int2 p6 = sepk[e + 12];
            const int2 p7 = sepk[e + 14];
            const unsigned v0 = *(const unsigned*)(Pn + (size_t)p0.x * OUT_FEAT + c2);
            const unsigned v1 = *(const unsigned*)(Pn + (size_t)p1.x * OUT_FEAT + c2);
            const unsigned v2 = *(const unsigned*)(Pn + (size_t)p2.x * OUT_FEAT + c2);
            const unsigned v3 = *(const unsigned*)(Pn + (size_t)p3.x * OUT_FEAT + c2);
            const unsigned v4 = *(const unsigned*)(Pn + (size_t)p4.x * OUT_FEAT + c2);
            const unsigned v5 = *(const unsigned*)(Pn + (size_t)p5.x * OUT_FEAT + c2);
            const unsigned v6 = *(const unsigned*)(Pn + (size_t)p6.x * OUT_FEAT + c2);
            const unsigned v7 = *(const unsigned*)(Pn + (size_t)p7.x * OUT_FEAT + c2);
            const float w0 = __int_as_float(p0.y);
            const float w1 = __int_as_float(p1.y);
            const float w2 = __int_as_float(p2.y);
            const float w3 = __int_as_float(p3.y);
            const float w4 = __int_as_float(p4.y);
            const float w5 = __int_as_float(p5.y);
            const float w6 = __int_as_float(p6.y);
            const float w7 = __int_as_float(p7.y);
            a0 += w0 * bflo(v0); a1 += w0 * bfhi(v0);
            b0 += w1 * bflo(v1); b1 += w1 * bfhi(v1);
            g0 += w2 * bflo(v2); g1 += w2 * bfhi(v2);
            h0 += w3 * bflo(v3); h1 += w3 * bfhi(v3);
            a0 += w4 * bflo(v4); a1 += w4 * bfhi(v4);
            b0 += w5 * bflo(v5); b1 += w5 * bfhi(v5);
            g0 += w6 * bflo(v6); g1 += w6 * bfhi(v6);
            h0 += w7 * bflo(v7); h1 += w7 * bfhi(v7);
        }
        for (; e + 6 < end; e += 8) {     // 4 edges per half
            const int2 p0 = sepk[e + 0];
            const int2 p1 = sepk[e + 2];
            const int2 p2 = sepk[e + 4];
            const int2 p3 = sepk[e + 6];
            const unsigned v0 = *(const unsigned*)(Pn + (size_t)p0.x * OUT_FEAT + c2);
            const unsigned v1 = *(const unsigned*)(Pn + (size_t)p1.x * OUT_FEAT + c2);
            const unsigned v2 = *(const unsigned*)(Pn + (size_t)p2.x * OUT_FEAT + c2);
            const unsigned v3 = *(const unsigned*)(Pn + (size_t)p3.x * OUT_FEAT + c2);
            const float w0 = __int_as_float(p0.y);
            const float w1 = __int_as_float(p1.y);
            const float w2 = __int_as_float(p2.y);
            const float w3 = __int_as_float(p3.y);
            a0 += w0 * bflo(v0); a1 += w0 * bfhi(v0);
            b0 += w1 * bflo(v1); b1 += w1 * bfhi(v1);
            g0 += w2 * bflo(v2); g1 += w2 * bfhi(v2);
            h0 += w3 * bflo(v3); h1 += w3 * bfhi(v3);
        }
        for (; e < end; e += 2) {
            const int2 p = sepk[e];
            const unsigned v = *(const unsigned*)(Pn + (size_t)p.x * OUT_FEAT + c2);
            const float w = __int_as_float(p.y);
            a0 += w * bflo(v); a1 += w * bfhi(v);
        }
        float s0 = (a0 + b0) + (g0 + h0);
        float s1 = (a1 + b1) + (g1 + h1);
        // combine even/odd halves (lanes differing in bit 5)
        s0 += __shfl_xor(s0, 32, 64);
        s1 += __shfl_xor(s1, 32, 64);
        if (half == 0) {
            const unsigned sv = *(const unsigned*)(accSelf + (size_t)dst * OUT_FEAT + c2);
            f32x2 o;
            o[0] = fmaxf(bflo(sv) + s0, 0.f);
            o[1] = fmaxf(bfhi(sv) + s1, 0.f);
            __builtin_nontemporal_store(o, (f32x2*)(out + (size_t)dst * OUT_FEAT + c2));
        }
    }
}

extern "C" void kernel_launch(void* const* d_in, const int* in_sizes, int n_in,
                              void* d_out, int out_size, void* d_ws, size_t ws_size,
                              hipStream_t stream) {
    const float* feat   = (const float*)d_in[0];
    const int*   esrc   = (const int*)  d_in[1];
    const int*   edst   = (const int*)  d_in[2];
    const float* ew     = (const float*)d_in[3];
    const float* Wself  = (const float*)d_in[4];
    const float* Wneigh = (const float*)d_in[5];

    const int n_nodes = in_sizes[0] / IN_FEAT;
    const int n_edges = in_sizes[1];
    const int NB = (n_nodes + BSZ - 1) / BSZ;        // 1563 buckets

    // workspace layout (~39.3 MB)
    bf16x8* Wfrag           = (bf16x8*)d_ws;                               // 64 KB
    unsigned short* accSelf = (unsigned short*)((char*)d_ws + 65536);      // N*64 bf16
    unsigned short* Pn      = accSelf + (size_t)n_nodes * OUT_FEAT;        // N*64 bf16
    int2*  binned  = (int2*)(Pn + (size_t)n_nodes * OUT_FEAT);             // 8*NB*CAP_SLICE int2
    int*   cnt     = (int*)(binned + (size_t)8 * NB * CAP_SLICE);          // 8*NB*16 ints (line-spread)
    float* out     = (float*)d_out;

    (void)hipMemsetAsync(cnt, 0, (size_t)8 * NB * CNT_STRIDE * sizeof(int), stream);

    wfrag_build<<<16, 256, 0, stream>>>(Wself, Wneigh, Wfrag);

    const int gblocks = (n_nodes + 63) / 64;                  // 782
    const int sblocks = (n_edges + 2047) / 2048;              // 782
    const int fblocks = (gblocks > sblocks) ? gblocks : sblocks;
    gemm_scatter<<<fblocks, 256, 0, stream>>>(
        feat, Wfrag, accSelf, Pn, esrc, edst, ew, cnt, binned, n_nodes, n_edges, NB);

    bucket_gather<<<NB, 256, 0, stream>>>(binned, cnt, Pn, accSelf, out, n_nodes, NB);
}